// Round 11
// baseline (244.115 us; speedup 1.0000x reference)
//
#include <hip/hip_runtime.h>
#include <stdint.h>

#define T 49
#define CCH 256

typedef __bf16 bf16x8 __attribute__((ext_vector_type(8)));
typedef float f32x4 __attribute__((ext_vector_type(4)));

static __device__ __forceinline__ unsigned short f2bf(float f){
  __bf16 h = (__bf16)f;
  return __builtin_bit_cast(unsigned short, h);
}
static __device__ __forceinline__ float bf2f(unsigned short h){
  return __builtin_bit_cast(float, ((uint32_t)h) << 16);
}
static __device__ __forceinline__ uint32_t pk2(float a, float b){
  return (uint32_t)f2bf(a) | ((uint32_t)f2bf(b) << 16);
}
static __device__ __forceinline__ f32x4 mfma16(bf16x8 a, bf16x8 b, f32x4 c){
  return __builtin_amdgcn_mfma_f32_16x16x32_bf16(a, b, c, 0, 0, 0);
}

static __device__ __forceinline__ bf16x8 build_frag(uint32_t lo_w0, uint32_t lo_w1,
                                                    uint32_t hi_w0, uint32_t hi_w1,
                                                    int srcA, int srcB, bool use_hi){
  uint32_t a0 = (uint32_t)__shfl((int)lo_w0, srcA, 64);
  uint32_t c0 = (uint32_t)__shfl((int)hi_w0, srcA, 64);
  uint32_t a1 = (uint32_t)__shfl((int)lo_w1, srcA, 64);
  uint32_t c1 = (uint32_t)__shfl((int)hi_w1, srcA, 64);
  uint32_t a2 = (uint32_t)__shfl((int)lo_w0, srcB, 64);
  uint32_t c2 = (uint32_t)__shfl((int)hi_w0, srcB, 64);
  uint32_t a3 = (uint32_t)__shfl((int)lo_w1, srcB, 64);
  uint32_t c3 = (uint32_t)__shfl((int)hi_w1, srcB, 64);
  uint4 u = use_hi ? make_uint4(c0, c1, c2, c3) : make_uint4(a0, a1, a2, a3);
  return __builtin_bit_cast(bf16x8, u);
}

// ---------------- prep kernels ----------------

// dense x f32 -> xg bf16 [50240][256] (rows >= 50176 zeroed)
__global__ void prep_xbf(const float* __restrict__ x, unsigned short* __restrict__ xg){
  const unsigned int NV = 50176u * 256u / 8u;   // 1605632 valid 8-chunks
  const unsigned int NT = 50240u * 256u / 8u;   // 1607680 total
  for (unsigned int idx = blockIdx.x * blockDim.x + threadIdx.x; idx < NT;
       idx += gridDim.x * blockDim.x){
    uint4 o;
    if (idx < NV){
      const float4 a = reinterpret_cast<const float4*>(x)[(size_t)idx * 2];
      const float4 c = reinterpret_cast<const float4*>(x)[(size_t)idx * 2 + 1];
      o = make_uint4(pk2(a.x, a.y), pk2(a.z, a.w), pk2(c.x, c.y), pk2(c.z, c.w));
    } else {
      o = make_uint4(0u, 0u, 0u, 0u);
    }
    reinterpret_cast<uint4*>(xg)[idx] = o;
  }
}

__global__ void prep_wqkvT(const float* __restrict__ wq, const float* __restrict__ wk,
                           const float* __restrict__ wv, unsigned short* __restrict__ out){
  int bk = blockIdx.x;            // 0..767
  int p = bk >> 8, kk = bk & 255;
  int n = threadIdx.x;
  const float* w = (p == 0) ? wq : (p == 1 ? wk : wv);
  float scl = (p == 0) ? 0.17677669529663687f : 1.0f;
  out[(size_t)(p * 256 + n) * 256 + kk] = f2bf(w[kk * 256 + n] * scl);
}

__global__ void prep_wodT(const float* __restrict__ wo, const float* __restrict__ dw,
                          unsigned short* __restrict__ out){
  int hd = blockIdx.x;            // 0..255
  int c = threadIdx.x;            // 0..255
  float s = 0.f;
  for (int cp = 0; cp < 256; ++cp) s = fmaf(wo[hd * 256 + cp], dw[cp * 256 + c], s);
  out[(size_t)c * 256 + hd] = f2bf(s);
}

__global__ void prep_misc(const int* __restrict__ rp, const float* __restrict__ btab,
                          const float* __restrict__ bq, const float* __restrict__ bk,
                          const float* __restrict__ bv, const float* __restrict__ bo,
                          const float* __restrict__ dwm, const float* __restrict__ db,
                          unsigned short* __restrict__ biasP, float* __restrict__ bqkv,
                          float* __restrict__ bod){
  int t = threadIdx.x;
  if (blockIdx.x == 0){
    for (int idx = t; idx < 768; idx += 256){
      int p = idx >> 8, n = idx & 255;
      float v = (p == 0) ? bq[n] * 0.17677669529663687f : (p == 1 ? bk[n] : bv[n]);
      bqkv[idx] = v;
    }
    float s = db[t];
    for (int cp = 0; cp < 256; ++cp) s = fmaf(bo[cp], dwm[cp * 256 + t], s);
    bod[t] = s;
  } else {
    int h = blockIdx.x - 1;
    for (int idx = t; idx < 4096; idx += 256){
      int r  = idx & 3;
      int lo = (idx >> 2) & 15;
      int g  = (idx >> 6) & 3;
      int nt = (idx >> 8) & 3;
      int jt = idx >> 10;
      int j = 16 * jt + 4 * g + r;
      int i = 16 * nt + lo;
      float v;
      if (j >= T) v = -1e30f;
      else if (i >= T) v = 0.f;
      else {
        int r0 = rp[i * 49 + j];
        int r1 = rp[2401 + i * 49 + j];
        v = btab[h * 169 + r0 * 13 + r1];
      }
      biasP[h * 4096 + idx] = f2bf(v);
    }
  }
}

// ---------------- fused QKV + attention: one wave per (b,h), NO LDS, NO barriers ----------------
// x frags read directly from dense xg (k-contiguous for both MFMA orientations;
// rows 49..63 of a window are the next window's tokens -> finite garbage, masked
// by the pre-masked bias; pad rows of the last window are zeros).
// Three QKV passes (32-AGPR acc each, r5-validated), chunked 12-load batches
// (r7-validated), in-register frag builds (r3-validated), attn body (r10-validated).
__launch_bounds__(256, 4)
__global__ void qkv_attn(const unsigned short* __restrict__ xg,
                         const unsigned short* __restrict__ wqkvT,
                         const float* __restrict__ bqkv,
                         const unsigned short* __restrict__ biasP,
                         unsigned short* __restrict__ og){
  const int tid  = threadIdx.x;
  const int wv_  = tid >> 6;
  const int lane = tid & 63;
  const int g    = lane >> 4;
  const int lo   = lane & 15;
  const int task = blockIdx.x * 4 + wv_;
  const int b    = task >> 3;
  const int h    = task & 7;

  const int  srcA = lo + 16 * ((2 * g) & 3);
  const int  srcB = lo + 16 * ((2 * g + 1) & 3);
  const bool ghi  = (g >= 2);

  const unsigned short* xw = xg + (size_t)b * 49 * 256;   // window rows 0..63

  bf16x8 av[2][2], fk[4], fq[4];

  // ---- pass V (normal GEMM): v[t][d]; acc[mt=4][nt=2] = 32 AGPR ----
  {
    f32x4 acc[4][2];
    #pragma unroll
    for (int mt = 0; mt < 4; ++mt)
      #pragma unroll
      for (int nt = 0; nt < 2; ++nt) acc[mt][nt] = f32x4{0,0,0,0};

    #pragma unroll 1
    for (int kb = 0; kb < 4; ++kb){
      bf16x8 xf[2][4], wf[2][2];
      #pragma unroll
      for (int q2 = 0; q2 < 2; ++q2){
        const int kt = kb * 2 + q2;
        #pragma unroll
        for (int mt = 0; mt < 4; ++mt)
          xf[q2][mt] = *reinterpret_cast<const bf16x8*>(
              xw + (size_t)(16 * mt + lo) * 256 + kt * 32 + 8 * g);
        #pragma unroll
        for (int nt = 0; nt < 2; ++nt)
          wf[q2][nt] = *reinterpret_cast<const bf16x8*>(
              wqkvT + (size_t)(512 + h * 32 + 16 * nt + lo) * 256 + kt * 32 + 8 * g);
      }
      #pragma unroll
      for (int q2 = 0; q2 < 2; ++q2)
        #pragma unroll
        for (int nt = 0; nt < 2; ++nt)
          #pragma unroll
          for (int mt = 0; mt < 4; ++mt)
            acc[mt][nt] = mfma16(xf[q2][mt], wf[q2][nt], acc[mt][nt]);
    }
    uint32_t pv[4][2][2];
    #pragma unroll
    for (int nt = 0; nt < 2; ++nt){
      const float bvs = bqkv[512 + h * 32 + 16 * nt + lo];
      #pragma unroll
      for (int mt = 0; mt < 4; ++mt){
        f32x4 t = acc[mt][nt];
        t[0] += bvs; t[1] += bvs; t[2] += bvs; t[3] += bvs;
        pv[mt][nt][0] = pk2(t[0], t[1]); pv[mt][nt][1] = pk2(t[2], t[3]);
      }
    }
    #pragma unroll
    for (int dt = 0; dt < 2; ++dt)
      #pragma unroll
      for (int ktj = 0; ktj < 2; ++ktj)
        av[dt][ktj] = build_frag(pv[2 * ktj][dt][0], pv[2 * ktj][dt][1],
                                 pv[2 * ktj + 1][dt][0], pv[2 * ktj + 1][dt][1],
                                 srcA, srcB, ghi);
  }

  // ---- pass K (transposed GEMM): kT[d][t]; acc[mt=2][nt=4] = 32 AGPR ----
  {
    f32x4 acc[2][4];
    #pragma unroll
    for (int mt = 0; mt < 2; ++mt)
      #pragma unroll
      for (int nt = 0; nt < 4; ++nt) acc[mt][nt] = f32x4{0,0,0,0};

    #pragma unroll 1
    for (int kb = 0; kb < 4; ++kb){
      bf16x8 xf[2][4], wf[2][2];
      #pragma unroll
      for (int q2 = 0; q2 < 2; ++q2){
        const int kt = kb * 2 + q2;
        #pragma unroll
        for (int nt = 0; nt < 4; ++nt)
          xf[q2][nt] = *reinterpret_cast<const bf16x8*>(
              xw + (size_t)(16 * nt + lo) * 256 + kt * 32 + 8 * g);
        #pragma unroll
        for (int mt = 0; mt < 2; ++mt)
          wf[q2][mt] = *reinterpret_cast<const bf16x8*>(
              wqkvT + (size_t)(256 + h * 32 + 16 * mt + lo) * 256 + kt * 32 + 8 * g);
      }
      #pragma unroll
      for (int q2 = 0; q2 < 2; ++q2)
        #pragma unroll
        for (int mt = 0; mt < 2; ++mt)
          #pragma unroll
          for (int nt = 0; nt < 4; ++nt)
            acc[mt][nt] = mfma16(wf[q2][mt], xf[q2][nt], acc[mt][nt]);
    }
    uint32_t pkk[2][4][2];
    #pragma unroll
    for (int mt = 0; mt < 2; ++mt){
      const float4 b4 = *reinterpret_cast<const float4*>(bqkv + 256 + h * 32 + 16 * mt + 4 * g);
      #pragma unroll
      for (int nt = 0; nt < 4; ++nt){
        f32x4 t = acc[mt][nt];
        t[0] += b4.x; t[1] += b4.y; t[2] += b4.z; t[3] += b4.w;
        pkk[mt][nt][0] = pk2(t[0], t[1]); pkk[mt][nt][1] = pk2(t[2], t[3]);
      }
    }
    #pragma unroll
    for (int nt = 0; nt < 4; ++nt)
      fk[nt] = build_frag(pkk[0][nt][0], pkk[0][nt][1], pkk[1][nt][0], pkk[1][nt][1],
                          srcA, srcB, ghi);
  }

  // ---- pass Q (transposed GEMM, scale folded in weights) ----
  {
    f32x4 acc[2][4];
    #pragma unroll
    for (int mt = 0; mt < 2; ++mt)
      #pragma unroll
      for (int nt = 0; nt < 4; ++nt) acc[mt][nt] = f32x4{0,0,0,0};

    #pragma unroll 1
    for (int kb = 0; kb < 4; ++kb){
      bf16x8 xf[2][4], wf[2][2];
      #pragma unroll
      for (int q2 = 0; q2 < 2; ++q2){
        const int kt = kb * 2 + q2;
        #pragma unroll
        for (int nt = 0; nt < 4; ++nt)
          xf[q2][nt] = *reinterpret_cast<const bf16x8*>(
              xw + (size_t)(16 * nt + lo) * 256 + kt * 32 + 8 * g);
        #pragma unroll
        for (int mt = 0; mt < 2; ++mt)
          wf[q2][mt] = *reinterpret_cast<const bf16x8*>(
              wqkvT + (size_t)(h * 32 + 16 * mt + lo) * 256 + kt * 32 + 8 * g);
      }
      #pragma unroll
      for (int q2 = 0; q2 < 2; ++q2)
        #pragma unroll
        for (int mt = 0; mt < 2; ++mt)
          #pragma unroll
          for (int nt = 0; nt < 4; ++nt)
            acc[mt][nt] = mfma16(wf[q2][mt], xf[q2][nt], acc[mt][nt]);
    }
    uint32_t pq[2][4][2];
    #pragma unroll
    for (int mt = 0; mt < 2; ++mt){
      const float4 b4 = *reinterpret_cast<const float4*>(bqkv + h * 32 + 16 * mt + 4 * g);
      #pragma unroll
      for (int nt = 0; nt < 4; ++nt){
        f32x4 t = acc[mt][nt];
        t[0] += b4.x; t[1] += b4.y; t[2] += b4.z; t[3] += b4.w;
        pq[mt][nt][0] = pk2(t[0], t[1]); pq[mt][nt][1] = pk2(t[2], t[3]);
      }
    }
    #pragma unroll
    for (int nt = 0; nt < 4; ++nt)
      fq[nt] = build_frag(pq[0][nt][0], pq[0][nt][1], pq[1][nt][0], pq[1][nt][1],
                          srcA, srcB, ghi);
  }

  // ---- attention (r10 attn_b body, frags already in registers) ----
  #pragma unroll 1
  for (int nt = 0; nt < 4; ++nt){
    uint2 bb[4];
    #pragma unroll
    for (int jt = 0; jt < 4; ++jt)
      bb[jt] = *reinterpret_cast<const uint2*>(
          biasP + h * 4096 + jt * 1024 + nt * 256 + (g * 16 + lo) * 4);
    f32x4 lacc[4];
    #pragma unroll
    for (int jt = 0; jt < 4; ++jt){
      lacc[jt] = mfma16(fk[jt], fq[nt], f32x4{0,0,0,0});
      lacc[jt][0] += bf2f((unsigned short)(bb[jt].x & 0xffff));
      lacc[jt][1] += bf2f((unsigned short)(bb[jt].x >> 16));
      lacc[jt][2] += bf2f((unsigned short)(bb[jt].y & 0xffff));
      lacc[jt][3] += bf2f((unsigned short)(bb[jt].y >> 16));
    }
    float m01a = fmaxf(fmaxf(lacc[0][0], lacc[0][1]), fmaxf(lacc[0][2], lacc[0][3]));
    float m01b = fmaxf(fmaxf(lacc[1][0], lacc[1][1]), fmaxf(lacc[1][2], lacc[1][3]));
    float m23a = fmaxf(fmaxf(lacc[2][0], lacc[2][1]), fmaxf(lacc[2][2], lacc[2][3]));
    float m23b = fmaxf(fmaxf(lacc[3][0], lacc[3][1]), fmaxf(lacc[3][2], lacc[3][3]));
    float m = fmaxf(fmaxf(m01a, m01b), fmaxf(m23a, m23b));
    m = fmaxf(m, __shfl_xor(m, 16, 64));
    m = fmaxf(m, __shfl_xor(m, 32, 64));
    float ssum = 0.f;
    uint32_t pw[4][2];
    #pragma unroll
    for (int jt = 0; jt < 4; ++jt){
      f32x4 t = lacc[jt];
      #pragma unroll
      for (int r = 0; r < 4; ++r){
        t[r] = exp2f((t[r] - m) * 1.4426950408889634f);
        ssum += t[r];
      }
      pw[jt][0] = pk2(t[0], t[1]);
      pw[jt][1] = pk2(t[2], t[3]);
    }
    ssum += __shfl_xor(ssum, 16, 64);
    ssum += __shfl_xor(ssum, 32, 64);
    const float r0 = 1.f / ssum;

    bf16x8 pf0 = build_frag(pw[0][0], pw[0][1], pw[1][0], pw[1][1], srcA, srcB, ghi);
    bf16x8 pf1 = build_frag(pw[2][0], pw[2][1], pw[3][0], pw[3][1], srcA, srcB, ghi);

    const int i = 16 * nt + lo;
    #pragma unroll
    for (int dt = 0; dt < 2; ++dt){
      f32x4 oacc = mfma16(av[dt][0], pf0, f32x4{0,0,0,0});
      oacc = mfma16(av[dt][1], pf1, oacc);
      if (i < T)
        *reinterpret_cast<uint2*>(og + ((size_t)b * T + i) * 256 + h * 32 + 16 * dt + 4 * g)
            = make_uint2(pk2(oacc[0] * r0, oacc[1] * r0), pk2(oacc[2] * r0, oacc[3] * r0));
    }
  }
}

// ---------------- kernel C: dense final GEMM, zero LDS (r10-validated) ----------------
__launch_bounds__(512, 4)
__global__ void out_c(const unsigned short* __restrict__ og,
                      const unsigned short* __restrict__ wodT,
                      const float* __restrict__ bod,
                      float* __restrict__ y){
  const int tid  = threadIdx.x;
  const int w    = tid >> 6;
  const int lane = tid & 63;
  const int g    = lane >> 4;
  const int lo   = lane & 15;
  const int tok0 = blockIdx.x * 64;

  f32x4 acc[2][4];
  #pragma unroll
  for (int mt = 0; mt < 2; ++mt)
    #pragma unroll
    for (int nt = 0; nt < 4; ++nt) acc[mt][nt] = f32x4{0,0,0,0};

  #pragma unroll 2
  for (int kt = 0; kt < 8; ++kt){
    bf16x8 aw[2], bo_[4];
    #pragma unroll
    for (int mt = 0; mt < 2; ++mt)
      aw[mt] = *reinterpret_cast<const bf16x8*>(
          wodT + (size_t)(32 * w + 16 * mt + lo) * 256 + kt * 32 + 8 * g);
    #pragma unroll
    for (int nt = 0; nt < 4; ++nt)
      bo_[nt] = *reinterpret_cast<const bf16x8*>(
          og + (size_t)(tok0 + 16 * nt + lo) * 256 + kt * 32 + 8 * g);
    #pragma unroll
    for (int mt = 0; mt < 2; ++mt)
      #pragma unroll
      for (int nt = 0; nt < 4; ++nt) acc[mt][nt] = mfma16(aw[mt], bo_[nt], acc[mt][nt]);
  }

  #pragma unroll
  for (int mt = 0; mt < 2; ++mt){
    const int cb = 32 * w + 16 * mt + 4 * g;
    const float4 b4 = *reinterpret_cast<const float4*>(bod + cb);
    #pragma unroll
    for (int nt = 0; nt < 4; ++nt){
      const int tok = tok0 + 16 * nt + lo;
      float4 o;
      o.x = acc[mt][nt][0] + b4.x;
      o.y = acc[mt][nt][1] + b4.y;
      o.z = acc[mt][nt][2] + b4.z;
      o.w = acc[mt][nt][3] + b4.w;
      *reinterpret_cast<float4*>(y + (size_t)tok * 256 + cb) = o;
    }
  }
}

// ---------------- launch ----------------
extern "C" void kernel_launch(void* const* d_in, const int* in_sizes, int n_in,
                              void* d_out, int out_size, void* d_ws, size_t ws_size,
                              hipStream_t stream){
  const float* x    = (const float*)d_in[0];
  const int*   rp   = (const int*)d_in[1];
  const float* btab = (const float*)d_in[2];
  const float* wq   = (const float*)d_in[3];
  const float* bq   = (const float*)d_in[4];
  const float* wk   = (const float*)d_in[5];
  const float* bk   = (const float*)d_in[6];
  const float* wv   = (const float*)d_in[7];
  const float* bv   = (const float*)d_in[8];
  const float* wo   = (const float*)d_in[9];
  const float* bo   = (const float*)d_in[10];
  const float* dw   = (const float*)d_in[11];
  const float* db   = (const float*)d_in[12];
  float* y = (float*)d_out;

  char* ws = (char*)d_ws;
  const size_t XG_BYTES = 25722880ull;   // 50240*256 bf16 (padded)
  const size_t OG_BYTES = 25690112ull;   // 50176*256 bf16

  unsigned short* xg = (unsigned short*)(ws);
  unsigned short* og = (unsigned short*)(ws + XG_BYTES);
  char* wsp = ws + XG_BYTES + OG_BYTES;
  unsigned short* wqkvT = (unsigned short*)(wsp);
  unsigned short* wodT  = (unsigned short*)(wsp + 393216);
  unsigned short* biasP = (unsigned short*)(wsp + 524288);
  float* bqkv           = (float*)(wsp + 589824);
  float* bod            = (float*)(wsp + 592896);

  prep_xbf<<<2048, 256, 0, stream>>>(x, xg);
  prep_wqkvT<<<768, 256, 0, stream>>>(wq, wk, wv, wqkvT);
  prep_wodT<<<256, 256, 0, stream>>>(wo, dw, wodT);
  prep_misc<<<9, 256, 0, stream>>>(rp, btab, bq, bk, bv, bo, dw, db, biasP, bqkv, bod);
  qkv_attn<<<2048, 256, 0, stream>>>(xg, wqkvT, bqkv, biasP, og);
  out_c<<<784, 512, 0, stream>>>(og, wodT, bod, y);
}

// Round 12
// 136.216 us; speedup vs baseline: 1.7921x; 1.7921x over previous
//
#include <hip/hip_runtime.h>
#include <stdint.h>

#define T 49
#define CCH 256

typedef __bf16 bf16x8 __attribute__((ext_vector_type(8)));
typedef float f32x4 __attribute__((ext_vector_type(4)));

static __device__ __forceinline__ unsigned short f2bf(float f){
  __bf16 h = (__bf16)f;
  return __builtin_bit_cast(unsigned short, h);
}
static __device__ __forceinline__ float bf2f(unsigned short h){
  return __builtin_bit_cast(float, ((uint32_t)h) << 16);
}
static __device__ __forceinline__ uint32_t pk2(float a, float b){
  return (uint32_t)f2bf(a) | ((uint32_t)f2bf(b) << 16);
}
static __device__ __forceinline__ f32x4 mfma16(bf16x8 a, bf16x8 b, f32x4 c){
  return __builtin_amdgcn_mfma_f32_16x16x32_bf16(a, b, c, 0, 0, 0);
}
#define SWZ(row) ((((row) & 7) << 4))

static __device__ __forceinline__ bf16x8 build_frag(uint32_t lo_w0, uint32_t lo_w1,
                                                    uint32_t hi_w0, uint32_t hi_w1,
                                                    int srcA, int srcB, bool use_hi){
  uint32_t a0 = (uint32_t)__shfl((int)lo_w0, srcA, 64);
  uint32_t c0 = (uint32_t)__shfl((int)hi_w0, srcA, 64);
  uint32_t a1 = (uint32_t)__shfl((int)lo_w1, srcA, 64);
  uint32_t c1 = (uint32_t)__shfl((int)hi_w1, srcA, 64);
  uint32_t a2 = (uint32_t)__shfl((int)lo_w0, srcB, 64);
  uint32_t c2 = (uint32_t)__shfl((int)hi_w0, srcB, 64);
  uint32_t a3 = (uint32_t)__shfl((int)lo_w1, srcB, 64);
  uint32_t c3 = (uint32_t)__shfl((int)hi_w1, srcB, 64);
  uint4 u = use_hi ? make_uint4(c0, c1, c2, c3) : make_uint4(a0, a1, a2, a3);
  return __builtin_bit_cast(bf16x8, u);
}

// ---------------- prep kernels (unchanged, validated) ----------------

__global__ void prep_wqkvT(const float* __restrict__ wq, const float* __restrict__ wk,
                           const float* __restrict__ wv, unsigned short* __restrict__ out){
  int bk = blockIdx.x;            // 0..767
  int p = bk >> 8, kk = bk & 255;
  int n = threadIdx.x;
  const float* w = (p == 0) ? wq : (p == 1 ? wk : wv);
  float scl = (p == 0) ? 0.17677669529663687f : 1.0f;
  out[(size_t)(p * 256 + n) * 256 + kk] = f2bf(w[kk * 256 + n] * scl);
}

__global__ void prep_wodT(const float* __restrict__ wo, const float* __restrict__ dw,
                          unsigned short* __restrict__ out){
  int hd = blockIdx.x;            // 0..255
  int c = threadIdx.x;            // 0..255
  float s = 0.f;
  for (int cp = 0; cp < 256; ++cp) s = fmaf(wo[hd * 256 + cp], dw[cp * 256 + c], s);
  out[(size_t)c * 256 + hd] = f2bf(s);
}

__global__ void prep_misc(const int* __restrict__ rp, const float* __restrict__ btab,
                          const float* __restrict__ bq, const float* __restrict__ bk,
                          const float* __restrict__ bv, const float* __restrict__ bo,
                          const float* __restrict__ dwm, const float* __restrict__ db,
                          unsigned short* __restrict__ biasP, float* __restrict__ bqkv,
                          float* __restrict__ bod){
  int t = threadIdx.x;
  if (blockIdx.x == 0){
    for (int idx = t; idx < 768; idx += 256){
      int p = idx >> 8, n = idx & 255;
      float v = (p == 0) ? bq[n] * 0.17677669529663687f : (p == 1 ? bk[n] : bv[n]);
      bqkv[idx] = v;
    }
    float s = db[t];
    for (int cp = 0; cp < 256; ++cp) s = fmaf(bo[cp], dwm[cp * 256 + t], s);
    bod[t] = s;
  } else {
    int h = blockIdx.x - 1;
    for (int idx = t; idx < 4096; idx += 256){
      int r  = idx & 3;
      int lo = (idx >> 2) & 15;
      int g  = (idx >> 6) & 3;
      int nt = (idx >> 8) & 3;
      int jt = idx >> 10;
      int j = 16 * jt + 4 * g + r;
      int i = 16 * nt + lo;
      float v;
      if (j >= T) v = -1e30f;
      else if (i >= T) v = 0.f;
      else {
        int r0 = rp[i * 49 + j];
        int r1 = rp[2401 + i * 49 + j];
        v = btab[h * 169 + r0 * 13 + r1];
      }
      biasP[h * 4096 + idx] = f2bf(v);
    }
  }
}

// ---------------- fused main kernel: base+immediate addressing ----------------
// r7/r8-validated structure (stage -> v -> k -> q -> attn -> final), with ALL
// hot-loop addresses reduced to per-lane base registers + compile-time
// immediates. xs: chunk ^ (row&7) swizzle -> 2 LDS bases (kt parity), imm
// mt*8192+(kt>>1)*128. vts: chunk ^ (d&3) swizzle -> 1 base, imm dt*2048+ktj*64.
// Weights/bias: 64-bit bases + kt*64 imm. Numerics bit-identical to round 8.
__launch_bounds__(512, 4)
__global__ void wmsa_main(const float* __restrict__ x,
                          const unsigned short* __restrict__ wqkvT,
                          const unsigned short* __restrict__ wodT,
                          const unsigned short* __restrict__ biasP,
                          const float* __restrict__ bqkv,
                          const float* __restrict__ bod,
                          float* __restrict__ y){
  __shared__ unsigned short xs[64 * 256];      // 32 KB, swizzle chunk^(row&7)
  __shared__ unsigned short vts[8 * 32 * 64];  // 32 KB, swizzle chunk^(d&3)

  const int b    = blockIdx.x;
  const int tid  = threadIdx.x;
  const int h    = tid >> 6;       // wave == head
  const int lane = tid & 63;
  const int g    = lane >> 4;
  const int lo   = lane & 15;
  char* xs_c  = (char*)xs;
  char* vts_c = (char*)vts;

  // ---- stage x -> xs (batched f32 loads -> bf16, zero pad rows, swizzled) ----
  const float* xbp = x + (size_t)b * T * CCH;
  {
    float4 vv[8];
    #pragma unroll
    for (int k2 = 0; k2 < 8; ++k2){
      int idx = tid + k2 * 512;
      int row = idx >> 6, c4 = idx & 63;
      vv[k2] = make_float4(0.f, 0.f, 0.f, 0.f);
      if (row < T) vv[k2] = reinterpret_cast<const float4*>(xbp)[row * 64 + c4];
    }
    #pragma unroll
    for (int k2 = 0; k2 < 8; ++k2){
      int idx = tid + k2 * 512;
      int row = idx >> 6, c4 = idx & 63;
      *reinterpret_cast<uint2*>(xs_c + row * 512 + ((c4 * 8) ^ SWZ(row)))
          = make_uint2(pk2(vv[k2].x, vv[k2].y), pk2(vv[k2].z, vv[k2].w));
    }
  }
  __syncthreads();

  // ---- per-lane constants & base registers ----
  const int  swz  = (lo & 7) << 4;
  const int  lo3  = lo & 3;
  const int  gq   = g >> 1;
  const int  gh   = (g & 1) * 8;
  const int  srcA = lo + 16 * ((2 * g) & 3);
  const int  srcB = lo + 16 * ((2 * g + 1) & 3);
  const bool ghi  = (g >= 2);

  // xs read bases: addr(mt,kt) = base[kt&1] + mt*8192 + (kt>>1)*128 (16-bit imm)
  const char* xb0 = xs_c + lo * 512 + ((16 * g) ^ swz);
  const char* xb1 = xs_c + lo * 512 + ((64 + 16 * g) ^ swz);
  // vts read base: addr(dt,ktj) = vr + dt*2048 + ktj*64
  const char* vr = vts_c + h * 4096 + lo * 128 + ((g ^ lo3) * 16);

  bf16x8 fk[4], fq[4];

  // ---- pass 1: v (normal GEMM) -> vts ----
  {
    const char* wv0 = (const char*)wqkvT + (size_t)(512 + h * 32 + lo) * 512 + 16 * g;
    const char* wv1 = wv0 + 16 * 512;
    f32x4 acc[4][2];
    #pragma unroll
    for (int mt = 0; mt < 4; ++mt)
      #pragma unroll
      for (int nt = 0; nt < 2; ++nt) acc[mt][nt] = f32x4{0,0,0,0};

    #pragma unroll 1
    for (int kb = 0; kb < 2; ++kb){
      const char* p0 = xb0 + kb * 256;
      const char* p1 = xb1 + kb * 256;
      const char* w0 = wv0 + kb * 256;
      const char* w1 = wv1 + kb * 256;
      bf16x8 wf[2][4];
      #pragma unroll
      for (int q = 0; q < 4; ++q){
        wf[0][q] = *reinterpret_cast<const bf16x8*>(w0 + q * 64);
        wf[1][q] = *reinterpret_cast<const bf16x8*>(w1 + q * 64);
      }
      #pragma unroll
      for (int q = 0; q < 4; ++q){
        bf16x8 ax[4];
        #pragma unroll
        for (int mt = 0; mt < 4; ++mt)
          ax[mt] = *reinterpret_cast<const bf16x8*>(((q & 1) ? p1 : p0) + mt * 8192 + (q >> 1) * 128);
        #pragma unroll
        for (int nt = 0; nt < 2; ++nt)
          #pragma unroll
          for (int mt = 0; mt < 4; ++mt) acc[mt][nt] = mfma16(ax[mt], wf[nt][q], acc[mt][nt]);
      }
    }
    // epilogue: +bias, store to vts (chunk^(d&3) swizzle)
    char* vw = vts_c + h * 4096 + lo * 128 + gh;
    #pragma unroll
    for (int nt = 0; nt < 2; ++nt){
      const float bvs = bqkv[512 + h * 32 + 16 * nt + lo];
      #pragma unroll
      for (int mt = 0; mt < 4; ++mt){
        f32x4 t = acc[mt][nt];
        *reinterpret_cast<uint2*>(vw + nt * 2048 + (((2 * mt + gq) ^ lo3) * 16))
            = make_uint2(pk2(t[0] + bvs, t[1] + bvs), pk2(t[2] + bvs, t[3] + bvs));
      }
    }
  }

  // ---- pass 2: k (transposed GEMM) -> fk frags ----
  {
    const char* wk0 = (const char*)wqkvT + (size_t)(256 + h * 32 + lo) * 512 + 16 * g;
    const char* wk1 = wk0 + 16 * 512;
    f32x4 acc[2][4];
    #pragma unroll
    for (int mt = 0; mt < 2; ++mt)
      #pragma unroll
      for (int nt = 0; nt < 4; ++nt) acc[mt][nt] = f32x4{0,0,0,0};

    #pragma unroll 1
    for (int kb = 0; kb < 2; ++kb){
      const char* p0 = xb0 + kb * 256;
      const char* p1 = xb1 + kb * 256;
      const char* w0 = wk0 + kb * 256;
      const char* w1 = wk1 + kb * 256;
      bf16x8 wf[2][4];
      #pragma unroll
      for (int q = 0; q < 4; ++q){
        wf[0][q] = *reinterpret_cast<const bf16x8*>(w0 + q * 64);
        wf[1][q] = *reinterpret_cast<const bf16x8*>(w1 + q * 64);
      }
      #pragma unroll
      for (int q = 0; q < 4; ++q){
        bf16x8 bx[4];
        #pragma unroll
        for (int nt = 0; nt < 4; ++nt)
          bx[nt] = *reinterpret_cast<const bf16x8*>(((q & 1) ? p1 : p0) + nt * 8192 + (q >> 1) * 128);
        #pragma unroll
        for (int mt = 0; mt < 2; ++mt)
          #pragma unroll
          for (int nt = 0; nt < 4; ++nt) acc[mt][nt] = mfma16(wf[mt][q], bx[nt], acc[mt][nt]);
      }
    }
    uint32_t pkk[2][4][2];
    #pragma unroll
    for (int mt = 0; mt < 2; ++mt){
      const float4 b4 = *reinterpret_cast<const float4*>(bqkv + 256 + h * 32 + 16 * mt + 4 * g);
      #pragma unroll
      for (int nt = 0; nt < 4; ++nt){
        f32x4 t = acc[mt][nt];
        t[0] += b4.x; t[1] += b4.y; t[2] += b4.z; t[3] += b4.w;
        pkk[mt][nt][0] = pk2(t[0], t[1]); pkk[mt][nt][1] = pk2(t[2], t[3]);
      }
    }
    #pragma unroll
    for (int nt = 0; nt < 4; ++nt)
      fk[nt] = build_frag(pkk[0][nt][0], pkk[0][nt][1], pkk[1][nt][0], pkk[1][nt][1], srcA, srcB, ghi);
  }

  // ---- pass 3: q (transposed GEMM, scale in weights) -> fq frags ----
  {
    const char* wq0 = (const char*)wqkvT + (size_t)(h * 32 + lo) * 512 + 16 * g;
    const char* wq1 = wq0 + 16 * 512;
    f32x4 acc[2][4];
    #pragma unroll
    for (int mt = 0; mt < 2; ++mt)
      #pragma unroll
      for (int nt = 0; nt < 4; ++nt) acc[mt][nt] = f32x4{0,0,0,0};

    #pragma unroll 1
    for (int kb = 0; kb < 2; ++kb){
      const char* p0 = xb0 + kb * 256;
      const char* p1 = xb1 + kb * 256;
      const char* w0 = wq0 + kb * 256;
      const char* w1 = wq1 + kb * 256;
      bf16x8 wf[2][4];
      #pragma unroll
      for (int q = 0; q < 4; ++q){
        wf[0][q] = *reinterpret_cast<const bf16x8*>(w0 + q * 64);
        wf[1][q] = *reinterpret_cast<const bf16x8*>(w1 + q * 64);
      }
      #pragma unroll
      for (int q = 0; q < 4; ++q){
        bf16x8 bx[4];
        #pragma unroll
        for (int nt = 0; nt < 4; ++nt)
          bx[nt] = *reinterpret_cast<const bf16x8*>(((q & 1) ? p1 : p0) + nt * 8192 + (q >> 1) * 128);
        #pragma unroll
        for (int mt = 0; mt < 2; ++mt)
          #pragma unroll
          for (int nt = 0; nt < 4; ++nt) acc[mt][nt] = mfma16(wf[mt][q], bx[nt], acc[mt][nt]);
      }
    }
    uint32_t pq[2][4][2];
    #pragma unroll
    for (int mt = 0; mt < 2; ++mt){
      const float4 b4 = *reinterpret_cast<const float4*>(bqkv + h * 32 + 16 * mt + 4 * g);
      #pragma unroll
      for (int nt = 0; nt < 4; ++nt){
        f32x4 t = acc[mt][nt];
        t[0] += b4.x; t[1] += b4.y; t[2] += b4.z; t[3] += b4.w;
        pq[mt][nt][0] = pk2(t[0], t[1]); pq[mt][nt][1] = pk2(t[2], t[3]);
      }
    }
    #pragma unroll
    for (int nt = 0; nt < 4; ++nt)
      fq[nt] = build_frag(pq[0][nt][0], pq[0][nt][1], pq[1][nt][0], pq[1][nt][1], srcA, srcB, ghi);
  }
  __syncthreads();   // all xs reads done; attention overwrites xs with 'out'

  // ---- streamed attention: per i-column-tile nt ----
  // av frags hoisted (vts: 1 base + imm); bias: 2 bases + imm.
  bf16x8 av[2][2];
  #pragma unroll
  for (int dt = 0; dt < 2; ++dt)
    #pragma unroll
    for (int ktj = 0; ktj < 2; ++ktj)
      av[dt][ktj] = *reinterpret_cast<const bf16x8*>(vr + dt * 2048 + ktj * 64);

  const char* bbase0 = (const char*)biasP + h * 8192 + (g * 16 + lo) * 8;
  const char* bbase1 = bbase0 + 4096;
  const int oslot0 = ((h * 4 + gq) ^ (lo & 7)) * 16;
  const int oslot1 = ((h * 4 + 2 + gq) ^ (lo & 7)) * 16;
  char* ow = xs_c + lo * 512 + gh;

  #pragma unroll 1
  for (int nt = 0; nt < 4; ++nt){
    const char* bn0 = bbase0 + nt * 512;
    const char* bn1 = bbase1 + nt * 512;
    uint2 bb[4];
    bb[0] = *reinterpret_cast<const uint2*>(bn0);
    bb[1] = *reinterpret_cast<const uint2*>(bn0 + 2048);
    bb[2] = *reinterpret_cast<const uint2*>(bn1);
    bb[3] = *reinterpret_cast<const uint2*>(bn1 + 2048);
    f32x4 lacc[4];
    #pragma unroll
    for (int jt = 0; jt < 4; ++jt){
      lacc[jt] = mfma16(fk[jt], fq[nt], f32x4{0,0,0,0});
      lacc[jt][0] += bf2f((unsigned short)(bb[jt].x & 0xffff));
      lacc[jt][1] += bf2f((unsigned short)(bb[jt].x >> 16));
      lacc[jt][2] += bf2f((unsigned short)(bb[jt].y & 0xffff));
      lacc[jt][3] += bf2f((unsigned short)(bb[jt].y >> 16));
    }
    float m01a = fmaxf(fmaxf(lacc[0][0], lacc[0][1]), fmaxf(lacc[0][2], lacc[0][3]));
    float m01b = fmaxf(fmaxf(lacc[1][0], lacc[1][1]), fmaxf(lacc[1][2], lacc[1][3]));
    float m23a = fmaxf(fmaxf(lacc[2][0], lacc[2][1]), fmaxf(lacc[2][2], lacc[2][3]));
    float m23b = fmaxf(fmaxf(lacc[3][0], lacc[3][1]), fmaxf(lacc[3][2], lacc[3][3]));
    float m = fmaxf(fmaxf(m01a, m01b), fmaxf(m23a, m23b));
    m = fmaxf(m, __shfl_xor(m, 16, 64));
    m = fmaxf(m, __shfl_xor(m, 32, 64));
    float ssum = 0.f;
    uint32_t pw[4][2];
    #pragma unroll
    for (int jt = 0; jt < 4; ++jt){
      f32x4 t = lacc[jt];
      #pragma unroll
      for (int r = 0; r < 4; ++r){
        t[r] = exp2f((t[r] - m) * 1.4426950408889634f);
        ssum += t[r];
      }
      pw[jt][0] = pk2(t[0], t[1]);
      pw[jt][1] = pk2(t[2], t[3]);
    }
    ssum += __shfl_xor(ssum, 16, 64);
    ssum += __shfl_xor(ssum, 32, 64);
    const float r0 = 1.f / ssum;

    bf16x8 pf0 = build_frag(pw[0][0], pw[0][1], pw[1][0], pw[1][1], srcA, srcB, ghi);
    bf16x8 pf1 = build_frag(pw[2][0], pw[2][1], pw[3][0], pw[3][1], srcA, srcB, ghi);

    f32x4 o0 = mfma16(av[0][0], pf0, f32x4{0,0,0,0});
    o0 = mfma16(av[0][1], pf1, o0);
    f32x4 o1 = mfma16(av[1][0], pf0, f32x4{0,0,0,0});
    o1 = mfma16(av[1][1], pf1, o1);
    *reinterpret_cast<uint2*>(ow + nt * 8192 + oslot0)
        = make_uint2(pk2(o0[0] * r0, o0[1] * r0), pk2(o0[2] * r0, o0[3] * r0));
    *reinterpret_cast<uint2*>(ow + nt * 8192 + oslot1)
        = make_uint2(pk2(o1[0] * r0, o1[1] * r0), pk2(o1[2] * r0, o1[3] * r0));
  }
  __syncthreads();

  // ---- final GEMM: y[i][c] = sum_hd out[i][hd] * wodT[c][hd] + bod[c] ----
  {
    const char* wo0 = (const char*)wodT + (size_t)(h * 32 + lo) * 512 + 16 * g;
    const char* wo1 = wo0 + 16 * 512;
    f32x4 facc[4][2];
    #pragma unroll
    for (int mt = 0; mt < 4; ++mt)
      #pragma unroll
      for (int nt = 0; nt < 2; ++nt) facc[mt][nt] = f32x4{0,0,0,0};

    #pragma unroll 1
    for (int kb = 0; kb < 2; ++kb){
      const char* p0 = xb0 + kb * 256;
      const char* p1 = xb1 + kb * 256;
      const char* w0 = wo0 + kb * 256;
      const char* w1 = wo1 + kb * 256;
      bf16x8 wf[2][4];
      #pragma unroll
      for (int q = 0; q < 4; ++q){
        wf[0][q] = *reinterpret_cast<const bf16x8*>(w0 + q * 64);
        wf[1][q] = *reinterpret_cast<const bf16x8*>(w1 + q * 64);
      }
      #pragma unroll
      for (int q = 0; q < 4; ++q){
        bf16x8 a[4];
        #pragma unroll
        for (int mt = 0; mt < 4; ++mt)
          a[mt] = *reinterpret_cast<const bf16x8*>(((q & 1) ? p1 : p0) + mt * 8192 + (q >> 1) * 128);
        #pragma unroll
        for (int nt = 0; nt < 2; ++nt)
          #pragma unroll
          for (int mt = 0; mt < 4; ++mt) facc[mt][nt] = mfma16(a[mt], wf[nt][q], facc[mt][nt]);
      }
    }
    #pragma unroll
    for (int nt = 0; nt < 2; ++nt){
      const int c = h * 32 + nt * 16 + lo;
      const float bd = bod[c];
      float* yb = y + (size_t)b * T * CCH + c;
      #pragma unroll
      for (int mt = 0; mt < 4; ++mt)
        #pragma unroll
        for (int r = 0; r < 4; ++r){
          int i = 16 * mt + 4 * g + r;
          if (i < T) yb[(size_t)i * CCH] = facc[mt][nt][r] + bd;
        }
    }
  }
}

// ---------------- launch ----------------
extern "C" void kernel_launch(void* const* d_in, const int* in_sizes, int n_in,
                              void* d_out, int out_size, void* d_ws, size_t ws_size,
                              hipStream_t stream){
  const float* x    = (const float*)d_in[0];
  const int*   rp   = (const int*)d_in[1];
  const float* btab = (const float*)d_in[2];
  const float* wq   = (const float*)d_in[3];
  const float* bq   = (const float*)d_in[4];
  const float* wk   = (const float*)d_in[5];
  const float* bk   = (const float*)d_in[6];
  const float* wv   = (const float*)d_in[7];
  const float* bv   = (const float*)d_in[8];
  const float* wo   = (const float*)d_in[9];
  const float* bo   = (const float*)d_in[10];
  const float* dw   = (const float*)d_in[11];
  const float* db   = (const float*)d_in[12];
  float* y = (float*)d_out;

  char* ws = (char*)d_ws;
  unsigned short* wqkvT = (unsigned short*)(ws);            // 393216 B
  unsigned short* wodT  = (unsigned short*)(ws + 393216);   // 131072 B
  unsigned short* biasP = (unsigned short*)(ws + 524288);   // 65536 B
  float* bqkv           = (float*)(ws + 589824);            // 3072 B
  float* bod            = (float*)(ws + 592896);            // 1024 B

  prep_wqkvT<<<768, 256, 0, stream>>>(wq, wk, wv, wqkvT);
  prep_wodT<<<256, 256, 0, stream>>>(wo, dw, wodT);
  prep_misc<<<9, 256, 0, stream>>>(rp, btab, bq, bk, bv, bo, dw, db, biasP, bqkv, bod);
  wmsa_main<<<1024, 512, 0, stream>>>(x, wqkvT, wodT, biasP, bqkv, bod, y);
}